// Round 9
// baseline (420.076 us; speedup 1.0000x reference)
//
#include <hip/hip_runtime.h>
#include <stdint.h>

#define TOKENS 16384
#define DDIM   1024
#define NEXP   64
#define NCOL   128              // 64 gate + 64 noise cols
#define MT     128              // tokens per GEMM block
#define KB     32               // k-tile
#define KSPLIT 4
#define KCH    (DDIM / KSPLIT)  // 256 k per block
#define NTT    (TOKENS / MT)    // 128 token tiles

// -------- device-global scratch (no d_ws) --------
__device__ float g_part[KSPLIT][TOKENS][NCOL];  // 32 MB split-K partial logits
__device__ float g_ps[NEXP];                    // sum of clean router probs per expert
__device__ float g_cnt[NEXP];                   // top-2 counts per expert
__device__ float g_spa[1];                      // sum of softplus

// ---------------- JAX threefry2x32 (20 rounds) ----------------
struct U2 { uint32_t a, b; };

__host__ __device__ constexpr U2 tf2x32(uint32_t k0, uint32_t k1,
                                        uint32_t x0, uint32_t x1) {
  uint32_t ks[3] = {k0, k1, k0 ^ k1 ^ 0x1BD11BDAu};
  const uint32_t rot[2][4] = {{13u, 15u, 26u, 6u}, {17u, 29u, 16u, 24u}};
  x0 += ks[0]; x1 += ks[1];
  for (int d = 0; d < 5; ++d) {
    for (int j = 0; j < 4; ++j) {
      uint32_t r = rot[d & 1][j];
      x0 += x1;
      x1 = (x1 << r) | (x1 >> (32u - r));
      x1 ^= x0;
    }
    x0 += ks[(d + 1) % 3];
    x1 += ks[(d + 2) % 3] + (uint32_t)(d + 1);
  }
  return U2{x0, x1};
}

// JAX >=0.5 partitionable threefry: bits[i] = xor-fold(tf(key, (0, i)))
__device__ inline uint32_t noise_bits(uint32_t i) {
  constexpr U2 NK = tf2x32(0u, 0u, 0u, 12345u);   // fold_in(key(0), 12345)
  U2 o = tf2x32(NK.a, NK.b, 0u, i);
  return o.a ^ o.b;
}

// XLA ErfInv32 (Giles polynomial)
__device__ inline float xla_erfinv(float x) {
  float w = -log1pf(-x * x);
  float p;
  if (w < 5.0f) {
    w = w - 2.5f;
    p = 2.81022636e-08f;
    p = 3.43273939e-07f + p * w;
    p = -3.5233877e-06f + p * w;
    p = -4.39150654e-06f + p * w;
    p = 0.00021858087f + p * w;
    p = -0.00125372503f + p * w;
    p = -0.00417768164f + p * w;
    p = 0.246640727f + p * w;
    p = 1.50140941f + p * w;
  } else {
    w = sqrtf(w) - 3.0f;
    p = -0.000200214257f;
    p = 0.000100950558f + p * w;
    p = 0.00134934322f + p * w;
    p = -0.00367342844f + p * w;
    p = 0.00573950773f + p * w;
    p = -0.0076224613f + p * w;
    p = 0.00943887047f + p * w;
    p = 1.00167406f + p * w;
    p = 2.83297682f + p * w;
  }
  return p * x;
}

__device__ inline float noise_normal(uint32_t i) {
  uint32_t bits = noise_bits(i);
  float f = __uint_as_float((bits >> 9) | 0x3f800000u) - 1.0f;  // [0,1)
  float u = f * 2.0f + (-0.99999994f);
  u = fmaxf(u, -0.99999994f);
  return 1.41421356237f * xla_erfinv(u);
}

__device__ inline float softplus_ref(float x) {
  return fmaxf(x, 0.0f) + log1pf(expf(-fabsf(x)));
}

// ---------------- wave(64) primitives ----------------
__device__ inline float wave_max64(float v) {
  #pragma unroll
  for (int off = 32; off; off >>= 1) v = fmaxf(v, __shfl_xor(v, off, 64));
  return v;
}
__device__ inline float wave_sum64(float v) {
  #pragma unroll
  for (int off = 32; off; off >>= 1) v += __shfl_xor(v, off, 64);
  return v;
}
__device__ inline void wave_argmax64(float v, int idx, float& mv, int& mi) {
  float bv = v; int bi = idx;
  #pragma unroll
  for (int off = 32; off; off >>= 1) {
    float ov = __shfl_xor(bv, off, 64);
    int   oi = __shfl_xor(bi, off, 64);
    if (ov > bv || (ov == bv && oi < bi)) { bv = ov; bi = oi; }
  }
  mv = bv; mi = bi;
}

// ---------------- K0: zero the loss accumulators ----------------
__global__ void init_kernel() {
  const int t = threadIdx.x;
  if (t < NEXP) { g_ps[t] = 0.0f; g_cnt[t] = 0.0f; }
  if (t == NEXP) g_spa[0] = 0.0f;
}

// ---------------- K1: split-K GEMM, 8x8 micro-tile (f32 VALU) ----------------
// block = 128 tokens x 128 cols x 256 k-chunk; grid = (128 token-tiles, 4 k-chunks)
__global__ __launch_bounds__(256)
void NoisyTopKRouter_57621281243491_kernel(
    const float* __restrict__ x, const float* __restrict__ wg,
    const float* __restrict__ wn) {
  __shared__ float xs[KB][MT + 4];     // x^T tile: xs[k][token]  [32][132]
  __shared__ float wsd[KB][NCOL + 4];  // W^T tile: wsd[k][col]   [32][132]

  const int tid = threadIdx.x;
  const int tx = tid & 15;    // col group: cols tx*8..+7
  const int ty = tid >> 4;    // row group: rows ty*8..+7 (0..15)
  const int tok0 = blockIdx.x * MT;
  const int k0   = blockIdx.y * KCH;

  float acc[8][8] = {};
  float4 xr0, xr1, xr2, xr3, wr0, wr1, wr2, wr3;

  const int srow = tid >> 3;         // 0..31 (+128it): staging row within 128
  const int sc4  = (tid & 7) * 4;    // 0..28: k offset

  // stage k-tile 0
  {
    int r0 = srow, r1 = srow + 32, r2 = srow + 64, r3 = srow + 96;
    xr0 = *(const float4*)&x[(size_t)(tok0 + r0) * DDIM + k0 + sc4];
    xr1 = *(const float4*)&x[(size_t)(tok0 + r1) * DDIM + k0 + sc4];
    xr2 = *(const float4*)&x[(size_t)(tok0 + r2) * DDIM + k0 + sc4];
    xr3 = *(const float4*)&x[(size_t)(tok0 + r3) * DDIM + k0 + sc4];
    wr0 = *(const float4*)&wg[(size_t)r0 * DDIM + k0 + sc4];
    wr1 = *(const float4*)&wg[(size_t)r1 * DDIM + k0 + sc4];
    wr2 = *(const float4*)&wn[(size_t)r0 * DDIM + k0 + sc4];
    wr3 = *(const float4*)&wn[(size_t)r1 * DDIM + k0 + sc4];
  }
  {
    int r0 = srow, r1 = srow + 32, r2 = srow + 64, r3 = srow + 96;
    xs[sc4+0][r0]=xr0.x; xs[sc4+1][r0]=xr0.y; xs[sc4+2][r0]=xr0.z; xs[sc4+3][r0]=xr0.w;
    xs[sc4+0][r1]=xr1.x; xs[sc4+1][r1]=xr1.y; xs[sc4+2][r1]=xr1.z; xs[sc4+3][r1]=xr1.w;
    xs[sc4+0][r2]=xr2.x; xs[sc4+1][r2]=xr2.y; xs[sc4+2][r2]=xr2.z; xs[sc4+3][r2]=xr2.w;
    xs[sc4+0][r3]=xr3.x; xs[sc4+1][r3]=xr3.y; xs[sc4+2][r3]=xr3.z; xs[sc4+3][r3]=xr3.w;
    wsd[sc4+0][r0]=wr0.x; wsd[sc4+1][r0]=wr0.y; wsd[sc4+2][r0]=wr0.z; wsd[sc4+3][r0]=wr0.w;
    wsd[sc4+0][r1]=wr1.x; wsd[sc4+1][r1]=wr1.y; wsd[sc4+2][r1]=wr1.z; wsd[sc4+3][r1]=wr1.w;
    wsd[sc4+0][r2]=wr2.x; wsd[sc4+1][r2]=wr2.y; wsd[sc4+2][r2]=wr2.z; wsd[sc4+3][r2]=wr2.w;
    wsd[sc4+0][r3]=wr3.x; wsd[sc4+1][r3]=wr3.y; wsd[sc4+2][r3]=wr3.z; wsd[sc4+3][r3]=wr3.w;
  }
  __syncthreads();

  const int NT2 = KCH / KB;  // 8
  for (int kt = 0; kt < NT2; ++kt) {
    if (kt + 1 < NT2) {    // prefetch next k-tile into registers
      const int kn = k0 + (kt + 1) * KB;
      int r0 = srow, r1 = srow + 32, r2 = srow + 64, r3 = srow + 96;
      xr0 = *(const float4*)&x[(size_t)(tok0 + r0) * DDIM + kn + sc4];
      xr1 = *(const float4*)&x[(size_t)(tok0 + r1) * DDIM + kn + sc4];
      xr2 = *(const float4*)&x[(size_t)(tok0 + r2) * DDIM + kn + sc4];
      xr3 = *(const float4*)&x[(size_t)(tok0 + r3) * DDIM + kn + sc4];
      wr0 = *(const float4*)&wg[(size_t)r0 * DDIM + kn + sc4];
      wr1 = *(const float4*)&wg[(size_t)r1 * DDIM + kn + sc4];
      wr2 = *(const float4*)&wn[(size_t)r0 * DDIM + kn + sc4];
      wr3 = *(const float4*)&wn[(size_t)r1 * DDIM + kn + sc4];
    }
    #pragma unroll
    for (int kk = 0; kk < KB; ++kk) {
      const float4 a0 = *(const float4*)&xs[kk][ty * 8];
      const float4 a1 = *(const float4*)&xs[kk][ty * 8 + 4];
      const float4 b0 = *(const float4*)&wsd[kk][tx * 8];
      const float4 b1 = *(const float4*)&wsd[kk][tx * 8 + 4];
      const float av[8] = {a0.x, a0.y, a0.z, a0.w, a1.x, a1.y, a1.z, a1.w};
      const float bv[8] = {b0.x, b0.y, b0.z, b0.w, b1.x, b1.y, b1.z, b1.w};
      #pragma unroll
      for (int i = 0; i < 8; ++i)
        #pragma unroll
        for (int j = 0; j < 8; ++j)
          acc[i][j] += av[i] * bv[j];
    }
    __syncthreads();
    if (kt + 1 < NT2) {
      int r0 = srow, r1 = srow + 32, r2 = srow + 64, r3 = srow + 96;
      xs[sc4+0][r0]=xr0.x; xs[sc4+1][r0]=xr0.y; xs[sc4+2][r0]=xr0.z; xs[sc4+3][r0]=xr0.w;
      xs[sc4+0][r1]=xr1.x; xs[sc4+1][r1]=xr1.y; xs[sc4+2][r1]=xr1.z; xs[sc4+3][r1]=xr1.w;
      xs[sc4+0][r2]=xr2.x; xs[sc4+1][r2]=xr2.y; xs[sc4+2][r2]=xr2.z; xs[sc4+3][r2]=xr2.w;
      xs[sc4+0][r3]=xr3.x; xs[sc4+1][r3]=xr3.y; xs[sc4+2][r3]=xr3.z; xs[sc4+3][r3]=xr3.w;
      wsd[sc4+0][r0]=wr0.x; wsd[sc4+1][r0]=wr0.y; wsd[sc4+2][r0]=wr0.z; wsd[sc4+3][r0]=wr0.w;
      wsd[sc4+0][r1]=wr1.x; wsd[sc4+1][r1]=wr1.y; wsd[sc4+2][r1]=wr1.z; wsd[sc4+3][r1]=wr1.w;
      wsd[sc4+0][r2]=wr2.x; wsd[sc4+1][r2]=wr2.y; wsd[sc4+2][r2]=wr2.z; wsd[sc4+3][r2]=wr2.w;
      wsd[sc4+0][r3]=wr3.x; wsd[sc4+1][r3]=wr3.y; wsd[sc4+2][r3]=wr3.z; wsd[sc4+3][r3]=wr3.w;
      __syncthreads();
    }
  }

  // write split-K partials (coalesced float4)
  float* dst = &g_part[blockIdx.y][0][0];
  #pragma unroll
  for (int i = 0; i < 8; ++i) {
    const int t = tok0 + ty * 8 + i;
    *(float4*)&dst[(size_t)t * NCOL + tx * 8] =
        make_float4(acc[i][0], acc[i][1], acc[i][2], acc[i][3]);
    *(float4*)&dst[(size_t)t * NCOL + tx * 8 + 4] =
        make_float4(acc[i][4], acc[i][5], acc[i][6], acc[i][7]);
  }
}

// ---------------- K2: sum partials + router epilogue ----------------
// grid = 256 blocks x 256 threads; wave = token, lane = expert; 64 tokens/block
__global__ __launch_bounds__(256)
void epilogue_kernel(float* __restrict__ out) {
  const int tid  = threadIdx.x;
  const int lane = tid & 63;
  const int w    = tid >> 6;    // 0..3
  const int tok0 = blockIdx.x * 64;

  float* out_rw  = out;                        // [16384][2]
  float* out_idx = out + 2 * TOKENS;           // [16384][2]
  float* out_rp  = out + 4 * TOKENS + 1;       // [16384][64]

  float ps_acc = 0.0f, sp_acc = 0.0f, c_acc = 0.0f;

  for (int it = 0; it < 16; ++it) {
    const int t = tok0 + w * 16 + it;
    const float cl = g_part[0][t][lane] + g_part[1][t][lane] +
                     g_part[2][t][lane] + g_part[3][t][lane];
    const float nl = g_part[0][t][NEXP + lane] + g_part[1][t][NEXP + lane] +
                     g_part[2][t][NEXP + lane] + g_part[3][t][NEXP + lane];

    // router_probs = softmax(clean)
    const float m  = wave_max64(cl);
    const float v  = expf(cl - m);
    const float Z  = wave_sum64(v);
    const float rp = v / Z;
    out_rp[(size_t)t * NEXP + lane] = rp;
    ps_acc += rp;

    // noisy logits
    const float ns  = softplus_ref(nl);
    sp_acc += ns;
    const float noi = noise_normal((uint32_t)(t * NEXP + lane));
    const float lgn = __fadd_rn(cl, __fmul_rn(noi, ns));

    const float m2 = wave_max64(lgn);
    const float v2 = expf(lgn - m2);
    const float Z2 = wave_sum64(v2);
    const float p  = v2 / Z2;

    float p1; int i1;
    wave_argmax64(p, lane, p1, i1);
    const float pm = (lane == i1) ? -3.402823466e38f : p;
    float p2; int i2;
    wave_argmax64(pm, lane, p2, i2);

    c_acc += (float)((lane == i1) + (lane == i2));

    if (lane == 0) {
      const float s = p1 + p2;
      out_rw[t * 2 + 0]  = p1 / s;
      out_rw[t * 2 + 1]  = p2 / s;
      out_idx[t * 2 + 0] = (float)i1;
      out_idx[t * 2 + 1] = (float)i2;
    }
  }

  // block-level reduce, then one atomicAdd set per block
  __shared__ float lps[4][NEXP];
  __shared__ float lcb[4][NEXP];
  __shared__ float lspw[4];
  lps[w][lane] = ps_acc;
  lcb[w][lane] = c_acc;
  const float spw = wave_sum64(sp_acc);
  if (lane == 0) lspw[w] = spw;
  __syncthreads();
  if (tid < NEXP) {
    atomicAdd(&g_ps[tid],  lps[0][tid] + lps[1][tid] + lps[2][tid] + lps[3][tid]);
    atomicAdd(&g_cnt[tid], lcb[0][tid] + lcb[1][tid] + lcb[2][tid] + lcb[3][tid]);
  }
  if (tid == 0) atomicAdd(&g_spa[0], lspw[0] + lspw[1] + lspw[2] + lspw[3]);
}

// ---------------- K3: finalize scalars (64 threads, 129 floats) ----------------
__global__ void finalize_kernel(float* __restrict__ out) {
  const int lane = threadIdx.x;
  float term = (g_cnt[lane] / (float)TOKENS) * (g_ps[lane] / (float)TOKENS);
  #pragma unroll
  for (int off = 32; off; off >>= 1) term += __shfl_xor(term, off, 64);
  if (lane == 0) {
    out[4 * TOKENS] = 0.64f * term;   // LOAD_BALANCE_WEIGHT * NUM_EXPERTS
    out[4 * TOKENS + 1 + TOKENS * NEXP] = g_spa[0] / (float)(TOKENS * NEXP);
  }
}

// ---------------- host ----------------
extern "C" void kernel_launch(void* const* d_in, const int* in_sizes, int n_in,
                              void* d_out, int out_size, void* d_ws, size_t ws_size,
                              hipStream_t stream) {
  const float* x  = (const float*)d_in[0];   // f32 [4,4096,1024]
  const float* wg = (const float*)d_in[1];   // f32 [64,1024]
  const float* wn = (const float*)d_in[2];   // f32 [64,1024]
  float* out = (float*)d_out;                // f32, 1114114 elements

  (void)d_ws; (void)ws_size;

  init_kernel<<<1, 128, 0, stream>>>();
  NoisyTopKRouter_57621281243491_kernel<<<dim3(NTT, KSPLIT), 256, 0, stream>>>(x, wg, wn);
  epilogue_kernel<<<TOKENS / 64, 256, 0, stream>>>(out);
  finalize_kernel<<<1, 64, 0, stream>>>(out);
}

// Round 10
// 235.686 us; speedup vs baseline: 1.7824x; 1.7824x over previous
//
#include <hip/hip_runtime.h>
#include <stdint.h>

#define TOKENS 16384
#define DDIM   1024
#define NEXP   64
#define NCOL   128            // 64 gate + 64 noise cols
#define MT     64             // tokens per block
#define KB     32             // k-tile
#define NBLK   (TOKENS / MT)  // 256 blocks

// -------- loss accumulators in device globals (zeroed by init_kernel) --------
__device__ float g_ps[NEXP];   // sum of clean router probs per expert
__device__ float g_cnt[NEXP];  // top-2 counts per expert
__device__ float g_spa[1];     // sum of softplus

// ---------------- JAX threefry2x32 (20 rounds) ----------------
struct U2 { uint32_t a, b; };

__host__ __device__ constexpr U2 tf2x32(uint32_t k0, uint32_t k1,
                                        uint32_t x0, uint32_t x1) {
  uint32_t ks[3] = {k0, k1, k0 ^ k1 ^ 0x1BD11BDAu};
  const uint32_t rot[2][4] = {{13u, 15u, 26u, 6u}, {17u, 29u, 16u, 24u}};
  x0 += ks[0]; x1 += ks[1];
  for (int d = 0; d < 5; ++d) {
    for (int j = 0; j < 4; ++j) {
      uint32_t r = rot[d & 1][j];
      x0 += x1;
      x1 = (x1 << r) | (x1 >> (32u - r));
      x1 ^= x0;
    }
    x0 += ks[(d + 1) % 3];
    x1 += ks[(d + 2) % 3] + (uint32_t)(d + 1);
  }
  return U2{x0, x1};
}

// JAX >=0.5 partitionable threefry: bits[i] = xor-fold(tf(key, (0, i)))
__device__ inline uint32_t noise_bits(uint32_t i) {
  constexpr U2 NK = tf2x32(0u, 0u, 0u, 12345u);   // fold_in(key(0), 12345)
  U2 o = tf2x32(NK.a, NK.b, 0u, i);
  return o.a ^ o.b;
}

// XLA ErfInv32 (Giles polynomial)
__device__ inline float xla_erfinv(float x) {
  float w = -log1pf(-x * x);
  float p;
  if (w < 5.0f) {
    w = w - 2.5f;
    p = 2.81022636e-08f;
    p = 3.43273939e-07f + p * w;
    p = -3.5233877e-06f + p * w;
    p = -4.39150654e-06f + p * w;
    p = 0.00021858087f + p * w;
    p = -0.00125372503f + p * w;
    p = -0.00417768164f + p * w;
    p = 0.246640727f + p * w;
    p = 1.50140941f + p * w;
  } else {
    w = sqrtf(w) - 3.0f;
    p = -0.000200214257f;
    p = 0.000100950558f + p * w;
    p = 0.00134934322f + p * w;
    p = -0.00367342844f + p * w;
    p = 0.00573950773f + p * w;
    p = -0.0076224613f + p * w;
    p = 0.00943887047f + p * w;
    p = 1.00167406f + p * w;
    p = 2.83297682f + p * w;
  }
  return p * x;
}

__device__ inline float noise_normal(uint32_t i) {
  uint32_t bits = noise_bits(i);
  float f = __uint_as_float((bits >> 9) | 0x3f800000u) - 1.0f;  // [0,1)
  float u = f * 2.0f + (-0.99999994f);
  u = fmaxf(u, -0.99999994f);
  return 1.41421356237f * xla_erfinv(u);
}

__device__ inline float softplus_ref(float x) {
  return fmaxf(x, 0.0f) + log1pf(expf(-fabsf(x)));
}

// ---------------- wave(64) primitives ----------------
__device__ inline float wave_max64(float v) {
  #pragma unroll
  for (int off = 32; off; off >>= 1) v = fmaxf(v, __shfl_xor(v, off, 64));
  return v;
}
__device__ inline float wave_sum64(float v) {
  #pragma unroll
  for (int off = 32; off; off >>= 1) v += __shfl_xor(v, off, 64);
  return v;
}
__device__ inline void wave_argmax64(float v, int idx, float& mv, int& mi) {
  float bv = v; int bi = idx;
  #pragma unroll
  for (int off = 32; off; off >>= 1) {
    float ov = __shfl_xor(bv, off, 64);
    int   oi = __shfl_xor(bi, off, 64);
    if (ov > bv || (ov == bv && oi < bi)) { bv = ov; bi = oi; }
  }
  mv = bv; mi = bi;
}

// ---------------- K0: zero loss accumulators ----------------
__global__ void init_kernel() {
  const int t = threadIdx.x;
  if (t < NEXP) { g_ps[t] = 0.0f; g_cnt[t] = 0.0f; }
  if (t == NEXP) g_spa[0] = 0.0f;
}

// ---------------- K1: fused dual GEMM (4x8 micro-tile) + router epilogue ----------------
// block = 64 tokens x 128 cols, 256 threads; logits stay in LDS.
__global__ __launch_bounds__(256)
void NoisyTopKRouter_57621281243491_kernel(
    const float* __restrict__ x, const float* __restrict__ wg,
    const float* __restrict__ wn, float* __restrict__ out) {
  __shared__ float xs[KB][MT + 4];     // x^T tile: xs[k][token]  [32][68]
  __shared__ float wsd[KB][NCOL + 4];  // W^T tile: wsd[k][col]   [32][132]
  __shared__ float lg[MT][NCOL + 4];   // logits: lg[token][col]  [64][132]

  const int tid = threadIdx.x;
  const int tx = tid & 15;    // col group: cols tx*8..+7
  const int ty = tid >> 4;    // token group: tokens ty*4..+3 (0..15)
  const int tok0 = blockIdx.x * MT;

  const int srow = tid >> 3;        // 0..31: staging row
  const int sc4  = (tid & 7) * 4;   // 0..28: staging k offset

  float acc[4][8] = {};
  float4 xr0, xr1, wr0, wr1, wr2, wr3;

  // ---- stage k-tile 0 ----
  xr0 = *(const float4*)&x[(size_t)(tok0 + srow) * DDIM + sc4];
  xr1 = *(const float4*)&x[(size_t)(tok0 + srow + 32) * DDIM + sc4];
  wr0 = *(const float4*)&wg[(size_t)srow * DDIM + sc4];
  wr1 = *(const float4*)&wg[(size_t)(srow + 32) * DDIM + sc4];
  wr2 = *(const float4*)&wn[(size_t)srow * DDIM + sc4];
  wr3 = *(const float4*)&wn[(size_t)(srow + 32) * DDIM + sc4];
  {
    int r = srow;
    xs[sc4+0][r]=xr0.x; xs[sc4+1][r]=xr0.y; xs[sc4+2][r]=xr0.z; xs[sc4+3][r]=xr0.w;
    xs[sc4+0][r+32]=xr1.x; xs[sc4+1][r+32]=xr1.y; xs[sc4+2][r+32]=xr1.z; xs[sc4+3][r+32]=xr1.w;
    wsd[sc4+0][r]=wr0.x; wsd[sc4+1][r]=wr0.y; wsd[sc4+2][r]=wr0.z; wsd[sc4+3][r]=wr0.w;
    wsd[sc4+0][r+32]=wr1.x; wsd[sc4+1][r+32]=wr1.y; wsd[sc4+2][r+32]=wr1.z; wsd[sc4+3][r+32]=wr1.w;
    wsd[sc4+0][r+64]=wr2.x; wsd[sc4+1][r+64]=wr2.y; wsd[sc4+2][r+64]=wr2.z; wsd[sc4+3][r+64]=wr2.w;
    wsd[sc4+0][r+96]=wr3.x; wsd[sc4+1][r+96]=wr3.y; wsd[sc4+2][r+96]=wr3.z; wsd[sc4+3][r+96]=wr3.w;
  }
  __syncthreads();

  const int NT = DDIM / KB;  // 32
  for (int kt = 0; kt < NT; ++kt) {
    if (kt + 1 < NT) {   // prefetch next k-tile into registers
      const int kn = (kt + 1) * KB;
      xr0 = *(const float4*)&x[(size_t)(tok0 + srow) * DDIM + kn + sc4];
      xr1 = *(const float4*)&x[(size_t)(tok0 + srow + 32) * DDIM + kn + sc4];
      wr0 = *(const float4*)&wg[(size_t)srow * DDIM + kn + sc4];
      wr1 = *(const float4*)&wg[(size_t)(srow + 32) * DDIM + kn + sc4];
      wr2 = *(const float4*)&wn[(size_t)srow * DDIM + kn + sc4];
      wr3 = *(const float4*)&wn[(size_t)(srow + 32) * DDIM + kn + sc4];
    }
    #pragma unroll
    for (int kk = 0; kk < KB; ++kk) {
      const float4 a  = *(const float4*)&xs[kk][ty * 4];       // broadcast
      const float4 b0 = *(const float4*)&wsd[kk][tx * 8];
      const float4 b1 = *(const float4*)&wsd[kk][tx * 8 + 4];
      const float av[4] = {a.x, a.y, a.z, a.w};
      const float bv[8] = {b0.x, b0.y, b0.z, b0.w, b1.x, b1.y, b1.z, b1.w};
      #pragma unroll
      for (int i = 0; i < 4; ++i)
        #pragma unroll
        for (int j = 0; j < 8; ++j)
          acc[i][j] += av[i] * bv[j];
    }
    __syncthreads();
    if (kt + 1 < NT) {
      int r = srow;
      xs[sc4+0][r]=xr0.x; xs[sc4+1][r]=xr0.y; xs[sc4+2][r]=xr0.z; xs[sc4+3][r]=xr0.w;
      xs[sc4+0][r+32]=xr1.x; xs[sc4+1][r+32]=xr1.y; xs[sc4+2][r+32]=xr1.z; xs[sc4+3][r+32]=xr1.w;
      wsd[sc4+0][r]=wr0.x; wsd[sc4+1][r]=wr0.y; wsd[sc4+2][r]=wr0.z; wsd[sc4+3][r]=wr0.w;
      wsd[sc4+0][r+32]=wr1.x; wsd[sc4+1][r+32]=wr1.y; wsd[sc4+2][r+32]=wr1.z; wsd[sc4+3][r+32]=wr1.w;
      wsd[sc4+0][r+64]=wr2.x; wsd[sc4+1][r+64]=wr2.y; wsd[sc4+2][r+64]=wr2.z; wsd[sc4+3][r+64]=wr2.w;
      wsd[sc4+0][r+96]=wr3.x; wsd[sc4+1][r+96]=wr3.y; wsd[sc4+2][r+96]=wr3.z; wsd[sc4+3][r+96]=wr3.w;
      __syncthreads();
    }
  }

  // dump logits to LDS
  #pragma unroll
  for (int i = 0; i < 4; ++i) {
    *(float4*)&lg[ty * 4 + i][tx * 8] =
        make_float4(acc[i][0], acc[i][1], acc[i][2], acc[i][3]);
    *(float4*)&lg[ty * 4 + i][tx * 8 + 4] =
        make_float4(acc[i][4], acc[i][5], acc[i][6], acc[i][7]);
  }
  __syncthreads();

  // ---- epilogue: one wave per token, lane = expert ----
  const int lane = tid & 63;
  const int w    = tid >> 6;   // wave 0..3

  float* out_rw  = out;                        // [16384][2]
  float* out_idx = out + 2 * TOKENS;           // [16384][2] (indices as f32)
  float* out_rp  = out + 4 * TOKENS + 1;       // [16384][64]

  float ps_acc = 0.0f, sp_acc = 0.0f, c_acc = 0.0f;

  for (int it = 0; it < MT / 4; ++it) {
    const int tok = w * (MT / 4) + it;
    const int t   = tok0 + tok;
    const float cl = lg[tok][lane];
    const float nl = lg[tok][NEXP + lane];

    // router_probs = softmax(clean)
    const float m  = wave_max64(cl);
    const float v  = expf(cl - m);
    const float Z  = wave_sum64(v);
    const float rp = v / Z;
    out_rp[(size_t)t * NEXP + lane] = rp;
    ps_acc += rp;

    // noisy logits
    const float ns  = softplus_ref(nl);
    sp_acc += ns;
    const float noi = noise_normal((uint32_t)(t * NEXP + lane));
    const float lgn = __fadd_rn(cl, __fmul_rn(noi, ns));

    const float m2 = wave_max64(lgn);
    const float v2 = expf(lgn - m2);
    const float Z2 = wave_sum64(v2);
    const float p  = v2 / Z2;

    float p1; int i1;
    wave_argmax64(p, lane, p1, i1);
    const float pm = (lane == i1) ? -3.402823466e38f : p;
    float p2; int i2;
    wave_argmax64(pm, lane, p2, i2);

    c_acc += (float)((lane == i1) + (lane == i2));

    if (lane == 0) {
      const float s = p1 + p2;
      out_rw[t * 2 + 0]  = p1 / s;
      out_rw[t * 2 + 1]  = p2 / s;
      out_idx[t * 2 + 0] = (float)i1;
      out_idx[t * 2 + 1] = (float)i2;
    }
  }

  // block-level reduce, then one atomicAdd set per block
  __shared__ float lps[4][NEXP];
  __shared__ float lcb[4][NEXP];
  __shared__ float lspw[4];
  lps[w][lane] = ps_acc;
  lcb[w][lane] = c_acc;
  const float spw = wave_sum64(sp_acc);
  if (lane == 0) lspw[w] = spw;
  __syncthreads();
  if (tid < NEXP) {
    atomicAdd(&g_ps[tid],  lps[0][tid] + lps[1][tid] + lps[2][tid] + lps[3][tid]);
    atomicAdd(&g_cnt[tid], lcb[0][tid] + lcb[1][tid] + lcb[2][tid] + lcb[3][tid]);
  }
  if (tid == 0) atomicAdd(&g_spa[0], lspw[0] + lspw[1] + lspw[2] + lspw[3]);
}

// ---------------- K2: finalize scalars (64 threads, 129 floats) ----------------
__global__ void finalize_kernel(float* __restrict__ out) {
  const int lane = threadIdx.x;
  float term = (g_cnt[lane] / (float)TOKENS) * (g_ps[lane] / (float)TOKENS);
  #pragma unroll
  for (int off = 32; off; off >>= 1) term += __shfl_xor(term, off, 64);
  if (lane == 0) {
    out[4 * TOKENS] = 0.64f * term;   // LOAD_BALANCE_WEIGHT * NUM_EXPERTS
    out[4 * TOKENS + 1 + TOKENS * NEXP] = g_spa[0] / (float)(TOKENS * NEXP);
  }
}

// ---------------- host ----------------
extern "C" void kernel_launch(void* const* d_in, const int* in_sizes, int n_in,
                              void* d_out, int out_size, void* d_ws, size_t ws_size,
                              hipStream_t stream) {
  const float* x  = (const float*)d_in[0];   // f32 [4,4096,1024]
  const float* wg = (const float*)d_in[1];   // f32 [64,1024]
  const float* wn = (const float*)d_in[2];   // f32 [64,1024]
  float* out = (float*)d_out;                // f32, 1114114 elements

  (void)d_ws; (void)ws_size;

  init_kernel<<<1, 128, 0, stream>>>();
  NoisyTopKRouter_57621281243491_kernel<<<NBLK, 256, 0, stream>>>(x, wg, wn, out);
  finalize_kernel<<<1, 64, 0, stream>>>(out);
}

// Round 11
// 216.215 us; speedup vs baseline: 1.9429x; 1.0901x over previous
//
#include <hip/hip_runtime.h>
#include <stdint.h>

#define TOKENS 16384
#define DDIM   1024
#define NEXP   64
#define NCOL   128              // 64 gate + 64 noise cols
#define MT     64               // tokens per GEMM block
#define KB     32               // k-tile
#define KSPLIT 2
#define KCH    (DDIM / KSPLIT)  // 512 k per block
#define NTT    (TOKENS / MT)    // 256 token tiles

// -------- device-global scratch --------
__device__ float g_part[KSPLIT][TOKENS][NCOL];  // 16 MB split-K partials
__device__ float g_ps[NEXP];                    // sum of clean router probs per expert
__device__ float g_cnt[NEXP];                   // top-2 counts per expert
__device__ float g_spa[1];                      // sum of softplus

// ---------------- JAX threefry2x32 (20 rounds) ----------------
struct U2 { uint32_t a, b; };

__host__ __device__ constexpr U2 tf2x32(uint32_t k0, uint32_t k1,
                                        uint32_t x0, uint32_t x1) {
  uint32_t ks[3] = {k0, k1, k0 ^ k1 ^ 0x1BD11BDAu};
  const uint32_t rot[2][4] = {{13u, 15u, 26u, 6u}, {17u, 29u, 16u, 24u}};
  x0 += ks[0]; x1 += ks[1];
  for (int d = 0; d < 5; ++d) {
    for (int j = 0; j < 4; ++j) {
      uint32_t r = rot[d & 1][j];
      x0 += x1;
      x1 = (x1 << r) | (x1 >> (32u - r));
      x1 ^= x0;
    }
    x0 += ks[(d + 1) % 3];
    x1 += ks[(d + 2) % 3] + (uint32_t)(d + 1);
  }
  return U2{x0, x1};
}

// JAX >=0.5 partitionable threefry: bits[i] = xor-fold(tf(key, (0, i)))
__device__ inline uint32_t noise_bits(uint32_t i) {
  constexpr U2 NK = tf2x32(0u, 0u, 0u, 12345u);   // fold_in(key(0), 12345)
  U2 o = tf2x32(NK.a, NK.b, 0u, i);
  return o.a ^ o.b;
}

// XLA ErfInv32 (Giles polynomial)
__device__ inline float xla_erfinv(float x) {
  float w = -log1pf(-x * x);
  float p;
  if (w < 5.0f) {
    w = w - 2.5f;
    p = 2.81022636e-08f;
    p = 3.43273939e-07f + p * w;
    p = -3.5233877e-06f + p * w;
    p = -4.39150654e-06f + p * w;
    p = 0.00021858087f + p * w;
    p = -0.00125372503f + p * w;
    p = -0.00417768164f + p * w;
    p = 0.246640727f + p * w;
    p = 1.50140941f + p * w;
  } else {
    w = sqrtf(w) - 3.0f;
    p = -0.000200214257f;
    p = 0.000100950558f + p * w;
    p = 0.00134934322f + p * w;
    p = -0.00367342844f + p * w;
    p = 0.00573950773f + p * w;
    p = -0.0076224613f + p * w;
    p = 0.00943887047f + p * w;
    p = 1.00167406f + p * w;
    p = 2.83297682f + p * w;
  }
  return p * x;
}

__device__ inline float noise_normal(uint32_t i) {
  uint32_t bits = noise_bits(i);
  float f = __uint_as_float((bits >> 9) | 0x3f800000u) - 1.0f;  // [0,1)
  float u = f * 2.0f + (-0.99999994f);
  u = fmaxf(u, -0.99999994f);
  return 1.41421356237f * xla_erfinv(u);
}

__device__ inline float softplus_ref(float x) {
  return fmaxf(x, 0.0f) + log1pf(expf(-fabsf(x)));
}

// ---------------- wave(64) primitives ----------------
__device__ inline float wave_max64(float v) {
  #pragma unroll
  for (int off = 32; off; off >>= 1) v = fmaxf(v, __shfl_xor(v, off, 64));
  return v;
}
__device__ inline float wave_sum64(float v) {
  #pragma unroll
  for (int off = 32; off; off >>= 1) v += __shfl_xor(v, off, 64);
  return v;
}
__device__ inline void wave_argmax64(float v, int idx, float& mv, int& mi) {
  float bv = v; int bi = idx;
  #pragma unroll
  for (int off = 32; off; off >>= 1) {
    float ov = __shfl_xor(bv, off, 64);
    int   oi = __shfl_xor(bi, off, 64);
    if (ov > bv || (ov == bv && oi < bi)) { bv = ov; bi = oi; }
  }
  mv = bv; mi = bi;
}

// interleaved column mapping: stride 12 words per 8-col group -> 2-way banks (free)
__device__ __forceinline__ int wcol(int c) { return c + ((c >> 3) << 2); }

// ---------------- K1: split-K GEMM, 8x8 micro-tile, 128 threads ----------------
// block = 64 tokens x 128 cols x 512 k; grid = (256 token-tiles, 2 k-halves)
__global__ __launch_bounds__(128)
void NoisyTopKRouter_57621281243491_kernel(
    const float* __restrict__ x, const float* __restrict__ wg,
    const float* __restrict__ wn) {
  // zero loss accumulators (done before epilogue kernel runs; kernel-boundary ordering)
  if (blockIdx.x == 0 && blockIdx.y == 0) {
    if (threadIdx.x < NEXP) { g_ps[threadIdx.x] = 0.0f; g_cnt[threadIdx.x] = 0.0f; }
    if (threadIdx.x == NEXP) g_spa[0] = 0.0f;
  }

  __shared__ float xs[KB][MT + 4];   // x^T tile: xs[k][token]  [32][68] = 8.7 KB
  __shared__ float wsd[KB][192];     // W^T tile: wsd[k][wcol(col)]     = 24.6 KB

  const int tid = threadIdx.x;
  const int tx = tid & 15;    // col group: cols tx*8..+7
  const int ty = tid >> 4;    // token group: tokens ty*8..+7 (0..7)
  const int tok0 = blockIdx.x * MT;
  const int k0   = blockIdx.y * KCH;

  const int stok = tid >> 1;         // 0..63: x staging token
  const int skb  = (tid & 1) * 16;   // x staging k offset (0 or 16)
  const int wcl  = tid;              // 0..127: W staging col
  const float* wrow = (wcl < NEXP) ? (wg + (size_t)wcl * DDIM)
                                   : (wn + (size_t)(wcl - NEXP) * DDIM);
  const int wc = wcol(wcl);

  float acc[8][8] = {};

  for (int kt = 0; kt < KCH / KB; ++kt) {   // 16 k-tiles
    const int kk0 = k0 + kt * KB;

    float4 xv[4], wv[8];
    #pragma unroll
    for (int it = 0; it < 4; ++it)
      xv[it] = *(const float4*)&x[(size_t)(tok0 + stok) * DDIM + kk0 + skb + it * 4];
    #pragma unroll
    for (int it = 0; it < 8; ++it)
      wv[it] = *(const float4*)&wrow[kk0 + it * 4];

    #pragma unroll
    for (int it = 0; it < 4; ++it) {
      const int kb = skb + it * 4;
      xs[kb + 0][stok] = xv[it].x; xs[kb + 1][stok] = xv[it].y;
      xs[kb + 2][stok] = xv[it].z; xs[kb + 3][stok] = xv[it].w;
    }
    #pragma unroll
    for (int it = 0; it < 8; ++it) {
      const int kb = it * 4;
      wsd[kb + 0][wc] = wv[it].x; wsd[kb + 1][wc] = wv[it].y;
      wsd[kb + 2][wc] = wv[it].z; wsd[kb + 3][wc] = wv[it].w;
    }
    __syncthreads();

    #pragma unroll
    for (int kk = 0; kk < KB; ++kk) {
      const float4 a0 = *(const float4*)&xs[kk][ty * 8];        // 2-way banks, broadcast
      const float4 a1 = *(const float4*)&xs[kk][ty * 8 + 4];
      const float4 b0 = *(const float4*)&wsd[kk][tx * 12];      // wcol(tx*8): 2-way banks
      const float4 b1 = *(const float4*)&wsd[kk][tx * 12 + 4];
      const float av[8] = {a0.x, a0.y, a0.z, a0.w, a1.x, a1.y, a1.z, a1.w};
      const float bv[8] = {b0.x, b0.y, b0.z, b0.w, b1.x, b1.y, b1.z, b1.w};
      #pragma unroll
      for (int i = 0; i < 8; ++i)
        #pragma unroll
        for (int j = 0; j < 8; ++j)
          acc[i][j] += av[i] * bv[j];
    }
    __syncthreads();
  }

  // write split-K partials (coalesced float4, plain column layout)
  float* dst = &g_part[blockIdx.y][0][0];
  #pragma unroll
  for (int i = 0; i < 8; ++i) {
    const size_t t = (size_t)(tok0 + ty * 8 + i);
    *(float4*)&dst[t * NCOL + tx * 8]     = make_float4(acc[i][0], acc[i][1], acc[i][2], acc[i][3]);
    *(float4*)&dst[t * NCOL + tx * 8 + 4] = make_float4(acc[i][4], acc[i][5], acc[i][6], acc[i][7]);
  }
}

// ---------------- K2: combine partials + router epilogue ----------------
// grid = 256 blocks x 256 threads; wave = token, lane = expert; 64 tokens/block
__global__ __launch_bounds__(256)
void epilogue_kernel(float* __restrict__ out) {
  const int tid  = threadIdx.x;
  const int lane = tid & 63;
  const int w    = tid >> 6;    // 0..3
  const int tok0 = blockIdx.x * 64;

  float* out_rw  = out;                        // [16384][2]
  float* out_idx = out + 2 * TOKENS;           // [16384][2]
  float* out_rp  = out + 4 * TOKENS + 1;       // [16384][64]

  float ps_acc = 0.0f, sp_acc = 0.0f, c_acc = 0.0f;

  for (int it = 0; it < 16; ++it) {
    const int t = tok0 + w * 16 + it;
    const float cl = g_part[0][t][lane] + g_part[1][t][lane];
    const float nl = g_part[0][t][NEXP + lane] + g_part[1][t][NEXP + lane];

    // router_probs = softmax(clean)
    const float m  = wave_max64(cl);
    const float v  = expf(cl - m);
    const float Z  = wave_sum64(v);
    const float rp = v / Z;
    out_rp[(size_t)t * NEXP + lane] = rp;
    ps_acc += rp;

    // noisy logits
    const float ns  = softplus_ref(nl);
    sp_acc += ns;
    const float noi = noise_normal((uint32_t)(t * NEXP + lane));
    const float lgn = __fadd_rn(cl, __fmul_rn(noi, ns));

    const float m2 = wave_max64(lgn);
    const float v2 = expf(lgn - m2);
    const float Z2 = wave_sum64(v2);
    const float p  = v2 / Z2;

    float p1; int i1;
    wave_argmax64(p, lane, p1, i1);
    const float pm = (lane == i1) ? -3.402823466e38f : p;
    float p2; int i2;
    wave_argmax64(pm, lane, p2, i2);

    c_acc += (float)((lane == i1) + (lane == i2));

    if (lane == 0) {
      const float s = p1 + p2;
      out_rw[t * 2 + 0]  = p1 / s;
      out_rw[t * 2 + 1]  = p2 / s;
      out_idx[t * 2 + 0] = (float)i1;
      out_idx[t * 2 + 1] = (float)i2;
    }
  }

  // block-level reduce, then one atomicAdd set per block
  __shared__ float lps[4][NEXP];
  __shared__ float lcb[4][NEXP];
  __shared__ float lspw[4];
  lps[w][lane] = ps_acc;
  lcb[w][lane] = c_acc;
  const float spw = wave_sum64(sp_acc);
  if (lane == 0) lspw[w] = spw;
  __syncthreads();
  if (tid < NEXP) {
    atomicAdd(&g_ps[tid],  lps[0][tid] + lps[1][tid] + lps[2][tid] + lps[3][tid]);
    atomicAdd(&g_cnt[tid], lcb[0][tid] + lcb[1][tid] + lcb[2][tid] + lcb[3][tid]);
  }
  if (tid == 0) atomicAdd(&g_spa[0], lspw[0] + lspw[1] + lspw[2] + lspw[3]);
}

// ---------------- K3: finalize scalars ----------------
__global__ void finalize_kernel(float* __restrict__ out) {
  const int lane = threadIdx.x;
  float term = (g_cnt[lane] / (float)TOKENS) * (g_ps[lane] / (float)TOKENS);
  #pragma unroll
  for (int off = 32; off; off >>= 1) term += __shfl_xor(term, off, 64);
  if (lane == 0) {
    out[4 * TOKENS] = 0.64f * term;   // LOAD_BALANCE_WEIGHT * NUM_EXPERTS
    out[4 * TOKENS + 1 + TOKENS * NEXP] = g_spa[0] / (float)(TOKENS * NEXP);
  }
}

// ---------------- host ----------------
extern "C" void kernel_launch(void* const* d_in, const int* in_sizes, int n_in,
                              void* d_out, int out_size, void* d_ws, size_t ws_size,
                              hipStream_t stream) {
  const float* x  = (const float*)d_in[0];   // f32 [4,4096,1024]
  const float* wg = (const float*)d_in[1];   // f32 [64,1024]
  const float* wn = (const float*)d_in[2];   // f32 [64,1024]
  float* out = (float*)d_out;                // f32, 1114114 elements

  (void)d_ws; (void)ws_size;

  NoisyTopKRouter_57621281243491_kernel<<<dim3(NTT, KSPLIT), 128, 0, stream>>>(x, wg, wn);
  epilogue_kernel<<<TOKENS / 64, 256, 0, stream>>>(out);
  finalize_kernel<<<1, 64, 0, stream>>>(out);
}